// Round 3
// baseline (930.152 us; speedup 1.0000x reference)
//
#include <hip/hip_runtime.h>

// PureLSTM: B=4096, T=512, I=32, H=16, fp32. One wave64 per batch element.
// Lane g owns gate row g (order i[0:16) f[16:32) g[32:48) o[48:64)).
// R2: pre-activation per lane (4 trans/step), 1 bpermute + 1 swizzle gate
// exchange, pk-FMA x-dot, 2-step-deep pinned prefetch.

constexpr int BATCH = 4096;
constexpr int SEQ   = 512;
constexpr int ISZ   = 32;
constexpr int HSZ   = 16;

typedef float v2f __attribute__((ext_vector_type(2)));

__device__ __forceinline__ float bperm_f(int byte_addr, float v) {
  return __int_as_float(__builtin_amdgcn_ds_bpermute(byte_addr, __float_as_int(v)));
}
__device__ __forceinline__ float swz_xor16(float v) {
  // BitMode: and=0x1F, or=0, xor=16 -> 0x401F (lane ^ 16 within each 32-half)
  return __int_as_float(__builtin_amdgcn_ds_swizzle(__float_as_int(v), 0x401F));
}
__device__ __forceinline__ float rl_f(float v, int l) {
  return __int_as_float(__builtin_amdgcn_readlane(__float_as_int(v), l));
}
__device__ __forceinline__ float rcpf_(float x) { return __builtin_amdgcn_rcpf(x); }

#define LOADX(buf, tt)                                                        \
  do {                                                                        \
    const float4* p_ = reinterpret_cast<const float4*>(xb + (size_t)(tt) * ISZ); \
    _Pragma("unroll") for (int q_ = 0; q_ < 8; ++q_) (buf)[q_] = p_[q_];      \
  } while (0)

// x-dot: xacc = bias + Wih_row . x_t  (as 2 float2 accumulators -> v_pk_fma)
#define XDOT(XA, buf)                                                         \
  do {                                                                        \
    (XA)[0] = bsum2;                                                          \
    (XA)[1] = zero2;                                                          \
    _Pragma("unroll") for (int q_ = 0; q_ < 8; ++q_) {                        \
      v2f lo_ = {(buf)[q_].x, (buf)[q_].y};                                   \
      v2f hi_ = {(buf)[q_].z, (buf)[q_].w};                                   \
      (XA)[0] = __builtin_elementwise_fma(w2[2 * q_], lo_, (XA)[0]);          \
      (XA)[1] = __builtin_elementwise_fma(w2[2 * q_ + 1], hi_, (XA)[1]);      \
    }                                                                         \
  } while (0)

// serial part of one timestep, consuming the 4 partial accumulators in XA
#define SERIAL(XA)                                                            \
  do {                                                                        \
    float a0 = (XA)[0].x, a1 = (XA)[0].y, a2 = (XA)[1].x, a3 = (XA)[1].y;     \
    _Pragma("unroll") for (int k_ = 0; k_ < HSZ; k_ += 4) {                   \
      a0 = fmaf(wh[k_ + 0], hs[k_ + 0], a0);                                  \
      a1 = fmaf(wh[k_ + 1], hs[k_ + 1], a1);                                  \
      a2 = fmaf(wh[k_ + 2], hs[k_ + 2], a2);                                  \
      a3 = fmaf(wh[k_ + 3], hs[k_ + 3], a3);                                  \
    }                                                                         \
    const float acc = (a0 + a1) + (a2 + a3);                                  \
    /* own-gate activation: sigmoid lanes (s=-1,a=1,b=0); tanh lanes via      \
       2*sigmoid(2x)-1 (s=-2,a=2,b=-1) */                                     \
    const float e_ = __expf(acc * s_);                                        \
    const float y  = fmaf(a_, rcpf_(1.f + e_), b_);                           \
    const float psw = bperm_f(adr_sw, y); /* value from lane^32 */            \
    /* q0: y=si,psw=tg -> si*tg ; q1: y=sf,psw=so -> sf*c ;                   \
       q2: y=tg,psw=si -> tg*si ; q3: y=so,psw=sf -> sf*c */                  \
    const float op1 = q3 ? psw : y;                                           \
    const float op2 = qodd ? c : psw;                                         \
    const float p   = op1 * op2;                                              \
    c = p + swz_xor16(p); /* pig + fc -> c_new, valid on all lanes */         \
    const float e2 = __expf(-2.f * c);                                        \
    const float th = fmaf(2.f, rcpf_(1.f + e2), -1.f);                        \
    const float oo = q1 ? psw : y; /* sigma_o at q1 (psw) and q3 (own) */     \
    const float hn = oo * th;      /* valid at lanes 16+j and 48+j */         \
    _Pragma("unroll") for (int k_ = 0; k_ < HSZ; ++k_)                        \
        hs[k_] = rl_f(hn, 16 + k_);                                           \
  } while (0)

__global__ __launch_bounds__(256, 4) void lstm_fused(
    const float* __restrict__ x, const float* __restrict__ Wih,
    const float* __restrict__ Whh, const float* __restrict__ bih,
    const float* __restrict__ bhh, const float* __restrict__ fcw,
    const float* __restrict__ fcb, float* __restrict__ out) {
  const int lane = threadIdx.x & 63;
  const int wid  = __builtin_amdgcn_readfirstlane(threadIdx.x >> 6);
  const int b    = blockIdx.x * 4 + wid;
  const int g    = lane;
  const int qd   = lane >> 4;
  const bool q1 = (qd == 1), q3 = (qd == 3);
  const bool qodd = q1 | q3;
  const bool isg  = (qd == 2);
  const float s_ = isg ? -2.f : -1.f;
  const float a_ = isg ?  2.f :  1.f;
  const float b_ = isg ? -1.f :  0.f;
  const int adr_sw = (lane ^ 32) << 2;

  // ---- per-lane weights in registers (as float2 pairs for pk-fma) ----
  v2f w2[ISZ / 2];
#pragma unroll
  for (int i = 0; i < ISZ / 4; ++i) {
    const float4 v = *reinterpret_cast<const float4*>(Wih + g * ISZ + 4 * i);
    w2[2 * i]     = {v.x, v.y};
    w2[2 * i + 1] = {v.z, v.w};
  }
  float wh[HSZ];
#pragma unroll
  for (int i = 0; i < HSZ; i += 4) {
    const float4 v = *reinterpret_cast<const float4*>(Whh + g * HSZ + i);
    wh[i] = v.x; wh[i + 1] = v.y; wh[i + 2] = v.z; wh[i + 3] = v.w;
  }
  const float bsum = bih[g] + bhh[g];
  const v2f bsum2 = {bsum, 0.f};
  const v2f zero2 = {0.f, 0.f};

  const float* xb = x + (size_t)b * (SEQ * ISZ);

  float hs[HSZ];  // uniform (SGPR via readlane)
#pragma unroll
  for (int k = 0; k < HSZ; ++k) hs[k] = 0.f;
  float c = 0.f;

  float4 bufA[8], bufB[8];
  LOADX(bufA, 0);
  LOADX(bufB, 1);
  v2f xa[2], xb2[2];

  for (int t = 0; t < SEQ; t += 2) {
    XDOT(xa, bufA);                       // consume bufA -> free to reload
    {
      const int tt = (t + 2 < SEQ) ? (t + 2) : 0;
      LOADX(bufA, tt);                    // prefetch distance = 2 steps
    }
    __builtin_amdgcn_sched_barrier(0);    // pin loads: don't sink below
    SERIAL(xa);

    XDOT(xb2, bufB);
    {
      const int tt = (t + 3 < SEQ) ? (t + 3) : 0;
      LOADX(bufB, tt);
    }
    __builtin_amdgcn_sched_barrier(0);
    SERIAL(xb2);
  }

  // ---- epilogue: out[b] = sigmoid(h . fc_w + fc_b) ----
  float s = fcb[0];
#pragma unroll
  for (int k = 0; k < HSZ; ++k) s = fmaf(hs[k], fcw[k], s);
  if (lane == 0) out[b] = rcpf_(1.f + __expf(-s));
}

extern "C" void kernel_launch(void* const* d_in, const int* in_sizes, int n_in,
                              void* d_out, int out_size, void* d_ws, size_t ws_size,
                              hipStream_t stream) {
  const float* x   = (const float*)d_in[0];
  const float* Wih = (const float*)d_in[1];
  const float* Whh = (const float*)d_in[2];
  const float* bih = (const float*)d_in[3];
  const float* bhh = (const float*)d_in[4];
  const float* fcw = (const float*)d_in[5];
  const float* fcb = (const float*)d_in[6];
  float* out = (float*)d_out;

  dim3 grid(BATCH / 4);
  dim3 block(256);
  hipLaunchKernelGGL(lstm_fused, grid, block, 0, stream,
                     x, Wih, Whh, bih, bhh, fcw, fcb, out);
}

// Round 4
// 576.149 us; speedup vs baseline: 1.6144x; 1.6144x over previous
//
#include <hip/hip_runtime.h>

// PureLSTM: B=4096, T=512, I=32, H=16, fp32. One wave64 per batch element.
// Lane g owns gate row g (order i[0:16) f[16:32) g[32:48) o[48:64)).
// R3: x staged into LDS in 32-step/4KB chunks via global_load_lds (async,
// double-buffered, per-wave private -> no barriers, vmcnt-gated). Recurrent
// loop reads x_t as wave-uniform ds_read_b128 broadcast. Gate math from R2
// (4 transcendentals/step, 1 bpermute + 1 swizzle combine).

constexpr int BATCH = 4096;
constexpr int SEQ   = 512;
constexpr int ISZ   = 32;
constexpr int HSZ   = 16;
constexpr int CH    = 32;        // timesteps per staged chunk (4 KB)
constexpr int NCH   = SEQ / CH;  // 16 chunks

typedef float v2f __attribute__((ext_vector_type(2)));
typedef float v4f __attribute__((ext_vector_type(4)));

__device__ __forceinline__ float bperm_f(int byte_addr, float v) {
  return __int_as_float(__builtin_amdgcn_ds_bpermute(byte_addr, __float_as_int(v)));
}
__device__ __forceinline__ float swz_xor16(float v) {
  // BitMode: and=0x1F, or=0, xor=16 -> lane ^ 16 within each 32-lane half
  return __int_as_float(__builtin_amdgcn_ds_swizzle(__float_as_int(v), 0x401F));
}
__device__ __forceinline__ float rl_f(float v, int l) {
  return __int_as_float(__builtin_amdgcn_readlane(__float_as_int(v), l));
}
__device__ __forceinline__ float rcpf_(float x) { return __builtin_amdgcn_rcpf(x); }

// Stage one 4KB chunk (32 timesteps) global -> LDS, async (4 x 1KB copies).
// LDS dest is wave-uniform base + lane*16 (HW rule); global src is per-lane.
__device__ __forceinline__ void stage_chunk(const float* gsrc, float* ldst,
                                            int lane) {
#pragma unroll
  for (int k = 0; k < 4; ++k) {
    __builtin_amdgcn_global_load_lds(
        (const __attribute__((address_space(1))) void*)(gsrc + k * 256 + lane * 4),
        (__attribute__((address_space(3))) void*)(ldst + k * 256), 16, 0, 0);
  }
}

__global__ __launch_bounds__(256, 4) void lstm_fused(
    const float* __restrict__ x, const float* __restrict__ Wih,
    const float* __restrict__ Whh, const float* __restrict__ bih,
    const float* __restrict__ bhh, const float* __restrict__ fcw,
    const float* __restrict__ fcb, float* __restrict__ out) {
  const int lane = threadIdx.x & 63;
  const int wid  = __builtin_amdgcn_readfirstlane(threadIdx.x >> 6);
  const int b    = blockIdx.x * 4 + wid;
  const int g    = lane;
  const int qd   = lane >> 4;
  const bool q1 = (qd == 1), q3 = (qd == 3);
  const bool qodd = q1 | q3;
  const bool isg  = (qd == 2);
  const float s_ = isg ? -2.f : -1.f;  // exp scale: tanh lanes use 2*sig(2x)-1
  const float a_ = isg ?  2.f :  1.f;
  const float b_ = isg ? -1.f :  0.f;
  const int adr_sw = (lane ^ 32) << 2;

  __shared__ float xs[4][2][CH * ISZ];  // 4 waves x dbuf x 4KB = 32KB/block

  // ---- per-lane weights in registers ----
  v2f w2lo[8], w2hi[8];
#pragma unroll
  for (int i = 0; i < 8; ++i) {
    const v4f wv = *reinterpret_cast<const v4f*>(Wih + g * ISZ + 4 * i);
    w2lo[i] = __builtin_shufflevector(wv, wv, 0, 1);
    w2hi[i] = __builtin_shufflevector(wv, wv, 2, 3);
  }
  float wh[HSZ];
#pragma unroll
  for (int i = 0; i < HSZ; i += 4) {
    const v4f v = *reinterpret_cast<const v4f*>(Whh + g * HSZ + i);
    wh[i] = v.x; wh[i + 1] = v.y; wh[i + 2] = v.z; wh[i + 3] = v.w;
  }
  const float bsum = bih[g] + bhh[g];

  const float* xb = x + (size_t)b * (SEQ * ISZ);

  float hs[HSZ];  // uniform h (readlane -> SGPR-resident)
#pragma unroll
  for (int k = 0; k < HSZ; ++k) hs[k] = 0.f;
  float c = 0.f;

  // ---- chunked recurrent loop ----
  stage_chunk(xb, &xs[wid][0][0], lane);  // chunk 0 -> buf 0
  int cur = 0;
  for (int ch = 0; ch < NCH; ++ch) {
    // prefetch next chunk into the other buffer (last iter: dummy restage)
    const int nch = (ch + 1 < NCH) ? (ch + 1) : (NCH - 1);
    stage_chunk(xb + (size_t)nch * (CH * ISZ), &xs[wid][cur ^ 1][0], lane);
    // wait for current buffer (all but the 4 just-issued loads)
    asm volatile("s_waitcnt vmcnt(4)" ::: "memory");

    const float* xc = &xs[wid][cur][0];
#pragma unroll 4
    for (int s = 0; s < CH; ++s) {
      // x-dot: acc = bias + Wih_row . x_t   (wave-uniform broadcast reads)
      const v4f* xp = reinterpret_cast<const v4f*>(xc + s * ISZ);
      v2f acc01 = {bsum, 0.f};
      v2f acc23 = {0.f, 0.f};
#pragma unroll
      for (int q = 0; q < 8; ++q) {
        const v4f xv = xp[q];
        const v2f lo = __builtin_shufflevector(xv, xv, 0, 1);
        const v2f hi = __builtin_shufflevector(xv, xv, 2, 3);
        acc01 = __builtin_elementwise_fma(w2lo[q], lo, acc01);
        acc23 = __builtin_elementwise_fma(w2hi[q], hi, acc23);
      }
      float a0 = acc01.x, a1 = acc01.y, a2 = acc23.x, a3 = acc23.y;
#pragma unroll
      for (int k = 0; k < HSZ; k += 4) {
        a0 = fmaf(wh[k + 0], hs[k + 0], a0);
        a1 = fmaf(wh[k + 1], hs[k + 1], a1);
        a2 = fmaf(wh[k + 2], hs[k + 2], a2);
        a3 = fmaf(wh[k + 3], hs[k + 3], a3);
      }
      const float acc = (a0 + a1) + (a2 + a3);
      // own-gate activation: sigmoid (q0,q1,q3) / tanh (q2) via 2*sig(2x)-1
      const float e_ = __expf(acc * s_);
      const float y  = fmaf(a_, rcpf_(1.f + e_), b_);
      const float psw = bperm_f(adr_sw, y);  // partner from lane^32
      // q0:(si,tg) q1:(sf,c) q2:(tg,si) q3:(sf<-psw,c)
      const float op1 = q3 ? psw : y;
      const float op2 = qodd ? c : psw;
      const float p   = op1 * op2;
      c = p + swz_xor16(p);  // i*g + f*c on every lane
      const float e2 = __expf(-2.f * c);
      const float th = fmaf(2.f, rcpf_(1.f + e2), -1.f);
      const float oo = q1 ? psw : y;  // sigma_o on q1(psw) and q3(own)
      const float hn = oo * th;       // valid on lanes 16..31 (and 48..63)
#pragma unroll
      for (int k = 0; k < HSZ; ++k) hs[k] = rl_f(hn, 16 + k);
    }
    cur ^= 1;
  }

  // ---- epilogue: out[b] = sigmoid(h . fc_w + fc_b) ----
  float s = fcb[0];
#pragma unroll
  for (int k = 0; k < HSZ; ++k) s = fmaf(hs[k], fcw[k], s);
  if (lane == 0) out[b] = rcpf_(1.f + __expf(-s));
}

extern "C" void kernel_launch(void* const* d_in, const int* in_sizes, int n_in,
                              void* d_out, int out_size, void* d_ws, size_t ws_size,
                              hipStream_t stream) {
  const float* x   = (const float*)d_in[0];
  const float* Wih = (const float*)d_in[1];
  const float* Whh = (const float*)d_in[2];
  const float* bih = (const float*)d_in[3];
  const float* bhh = (const float*)d_in[4];
  const float* fcw = (const float*)d_in[5];
  const float* fcb = (const float*)d_in[6];
  float* out = (float*)d_out;

  dim3 grid(BATCH / 4);
  dim3 block(256);
  hipLaunchKernelGGL(lstm_fused, grid, block, 0, stream,
                     x, Wih, Whh, bih, bhh, fcw, fcb, out);
}

// Round 7
// 458.243 us; speedup vs baseline: 2.0298x; 1.2573x over previous
//
#include <hip/hip_runtime.h>

// PureLSTM: B=4096, T=512, I=32, H=16. One wave64 per batch element.
// R5 = R4 with __fp16 builtin types fixed (+XGS 65->66):
//  - per-chunk x-dot via mfma_f32_16x16x32_f16 (xg -> per-wave LDS, bias in C)
//  - serial loop: 1 ds_read_b32/step for own-gate xg, 8 v_dot2_f32_f16 h-dot
//  - gate exchange: v_permlane32_swap (xor-recovery) + 1 ds_swizzle(xor16)
//  - h broadcast as packed f16 pairs: swizzle(xor1)+cvt_pkrtz, 8 readlanes

constexpr int BATCH = 4096;
constexpr int SEQ   = 512;
constexpr int ISZ   = 32;
constexpr int HSZ   = 16;
constexpr int CH    = 32;        // timesteps per chunk
constexpr int NCH   = SEQ / CH;  // 16 chunks
constexpr int XGS   = 66;        // xg LDS row stride (floats): writes 2-way, reads 2-way

typedef __fp16 h2  __attribute__((ext_vector_type(2)));
typedef __fp16 v8h __attribute__((ext_vector_type(8)));
typedef float  v4f __attribute__((ext_vector_type(4)));

union H8 { v8h v; h2 h[4]; };

__device__ __forceinline__ float swz_xor16(float v) {
  return __int_as_float(__builtin_amdgcn_ds_swizzle(__float_as_int(v), 0x401F));
}
__device__ __forceinline__ float swz_xor1(float v) {
  return __int_as_float(__builtin_amdgcn_ds_swizzle(__float_as_int(v), 0x041F));
}
__device__ __forceinline__ float rcpf_(float x) { return __builtin_amdgcn_rcpf(x); }
__device__ __forceinline__ float rl_f(float v, int l) {
  return __int_as_float(__builtin_amdgcn_readlane(__float_as_int(v), l));
}

__global__ __launch_bounds__(256, 4) void lstm_fused(
    const float* __restrict__ x, const float* __restrict__ Wih,
    const float* __restrict__ Whh, const float* __restrict__ bih,
    const float* __restrict__ bhh, const float* __restrict__ fcw,
    const float* __restrict__ fcb, float* __restrict__ out) {
  const int lane = threadIdx.x & 63;
  const int wid  = __builtin_amdgcn_readfirstlane(threadIdx.x >> 6);
  const int bidx = blockIdx.x * 4 + wid;
  const int col  = lane & 15;   // MFMA col / within-gate index
  const int kg   = lane >> 4;   // MFMA k-group / gate quarter
  const bool q1  = (kg == 1);   // f-lanes
  const bool q3  = (kg == 3);   // o-lanes
  const bool isg = (kg == 2);   // g-lanes: tanh pre-activation
  const float sS = isg ? -2.f : -1.f;
  const float sA = isg ?  2.f :  1.f;
  const float sB = isg ? -1.f :  0.f;

  __shared__ float xg_s[4][CH * XGS];  // per-wave private xg (33792 B/block)

  // ---- B-fragments: Wih as f16, B[k][n] with n=col, k=kg*8+e ----
  H8 bfr[4];
  float bb[4];
#pragma unroll
  for (int nt = 0; nt < 4; ++nt) {
    const int g = nt * 16 + col;
    const float* wp = Wih + g * ISZ + kg * 8;
    const v4f w0 = *reinterpret_cast<const v4f*>(wp);
    const v4f w1 = *reinterpret_cast<const v4f*>(wp + 4);
    bfr[nt].h[0] = __builtin_amdgcn_cvt_pkrtz(w0.x, w0.y);
    bfr[nt].h[1] = __builtin_amdgcn_cvt_pkrtz(w0.z, w0.w);
    bfr[nt].h[2] = __builtin_amdgcn_cvt_pkrtz(w1.x, w1.y);
    bfr[nt].h[3] = __builtin_amdgcn_cvt_pkrtz(w1.z, w1.w);
    bb[nt] = bih[g] + bhh[g];  // bias folded into MFMA C
  }

  // ---- Whh row for own gate (row = lane) as packed f16 pairs ----
  int whh[8];
  {
    const float* wp = Whh + lane * HSZ;
#pragma unroll
    for (int j = 0; j < 4; ++j) {
      const v4f v = *reinterpret_cast<const v4f*>(wp + 4 * j);
      whh[2 * j]     = __builtin_bit_cast(int, __builtin_amdgcn_cvt_pkrtz(v.x, v.y));
      whh[2 * j + 1] = __builtin_bit_cast(int, __builtin_amdgcn_cvt_pkrtz(v.z, v.w));
    }
  }

  const float* xb_ = x + (size_t)bidx * (SEQ * ISZ);
  const int aoff0 = col * ISZ + kg * 8;         // A tile mt=0 (t rows 0..15)
  const int aoff1 = (16 + col) * ISZ + kg * 8;  // A tile mt=1

  // prefetch chunk 0 x into registers (per-lane dense, 4KB/wave/chunk)
  v4f pf[4];
  pf[0] = *reinterpret_cast<const v4f*>(xb_ + aoff0);
  pf[1] = *reinterpret_cast<const v4f*>(xb_ + aoff0 + 4);
  pf[2] = *reinterpret_cast<const v4f*>(xb_ + aoff1);
  pf[3] = *reinterpret_cast<const v4f*>(xb_ + aoff1 + 4);

  // xg LDS pointers
  float* wbase = &xg_s[wid][(kg * 4) * XGS + col];  // MFMA D write base
  const float* xrd = &xg_s[wid][lane];              // serial read base (g=lane)

  int hs_pk[8];  // packed f16 h pairs (uniform via readlane)
#pragma unroll
  for (int j = 0; j < 8; ++j) hs_pk[j] = 0;
  float c = 0.f, hlast = 0.f;

  for (int ch = 0; ch < NCH; ++ch) {
    // convert current x regs -> A fragments
    H8 afr0, afr1;
    afr0.h[0] = __builtin_amdgcn_cvt_pkrtz(pf[0].x, pf[0].y);
    afr0.h[1] = __builtin_amdgcn_cvt_pkrtz(pf[0].z, pf[0].w);
    afr0.h[2] = __builtin_amdgcn_cvt_pkrtz(pf[1].x, pf[1].y);
    afr0.h[3] = __builtin_amdgcn_cvt_pkrtz(pf[1].z, pf[1].w);
    afr1.h[0] = __builtin_amdgcn_cvt_pkrtz(pf[2].x, pf[2].y);
    afr1.h[1] = __builtin_amdgcn_cvt_pkrtz(pf[2].z, pf[2].w);
    afr1.h[2] = __builtin_amdgcn_cvt_pkrtz(pf[3].x, pf[3].y);
    afr1.h[3] = __builtin_amdgcn_cvt_pkrtz(pf[3].z, pf[3].w);

    // issue next-chunk x loads (prefetch distance = 1 chunk = 32 steps)
    {
      const int nc = (ch + 1 < NCH) ? (ch + 1) : 0;
      const float* nx = xb_ + (size_t)nc * (CH * ISZ);
      pf[0] = *reinterpret_cast<const v4f*>(nx + aoff0);
      pf[1] = *reinterpret_cast<const v4f*>(nx + aoff0 + 4);
      pf[2] = *reinterpret_cast<const v4f*>(nx + aoff1);
      pf[3] = *reinterpret_cast<const v4f*>(nx + aoff1 + 4);
    }
    __builtin_amdgcn_sched_barrier(0);  // pin prefetch issue here

    // xg = x . Wih^T + bias : 8 MFMAs, D -> per-wave LDS
#pragma unroll
    for (int nt = 0; nt < 4; ++nt) {
      const v4f ci = {bb[nt], bb[nt], bb[nt], bb[nt]};
      const v4f d0 = __builtin_amdgcn_mfma_f32_16x16x32_f16(afr0.v, bfr[nt].v, ci, 0, 0, 0);
      const v4f d1 = __builtin_amdgcn_mfma_f32_16x16x32_f16(afr1.v, bfr[nt].v, ci, 0, 0, 0);
#pragma unroll
      for (int r = 0; r < 4; ++r) {
        wbase[r * XGS + nt * 16]        = d0[r];  // t = kg*4+r
        wbase[(16 + r) * XGS + nt * 16] = d1[r];  // t = 16+kg*4+r
      }
    }

    // ---- serial 32 steps ----
    float xcur = xrd[0];
#pragma unroll
    for (int s = 0; s < CH; ++s) {
      const float xnxt = xrd[(s + 1 < CH) ? (s + 1) * XGS : 0];
      // h-dot: 8 x v_dot2_f32_f16, two chains
      float a0 = xcur, a1 = 0.f;
#pragma unroll
      for (int j = 0; j < 4; ++j) {
        a0 = __builtin_amdgcn_fdot2(__builtin_bit_cast(h2, whh[j]),
                                    __builtin_bit_cast(h2, hs_pk[j]), a0, false);
        a1 = __builtin_amdgcn_fdot2(__builtin_bit_cast(h2, whh[j + 4]),
                                    __builtin_bit_cast(h2, hs_pk[j + 4]), a1, false);
      }
      const float pre = a0 + a1;
      // own-gate activation (sigmoid; tanh on g-lanes via 2*sig(2x)-1)
      const float e_ = __expf(pre * sS);
      const float y  = fmaf(sA, rcpf_(1.f + e_), sB);
      // partner = value at lane^32: permlane32_swap + xor recovery
      int va = __float_as_int(y), vb = va;
      asm volatile("s_nop 0\n\tv_permlane32_swap_b32 %0, %1\n\ts_nop 0"
                   : "+v"(va), "+v"(vb));
      const float prt = __int_as_float(va ^ vb ^ __float_as_int(y));
      // i/g lanes both compute i*g; xor16 ships it to f/o lanes
      const float p1  = y * prt;
      const float p1x = swz_xor16(p1);
      const float sf  = q3 ? prt : y;   // sigma_f on f(own) and o(partner)
      c = fmaf(sf, c, p1x);             // valid (duplicated) on f and o lanes
      const float e2 = __expf(-2.f * c);
      const float th = fmaf(2.f, rcpf_(1.f + e2), -1.f);
      const float so = q1 ? prt : y;    // sigma_o on f(partner) and o(own)
      hlast = so * th;                  // h_k on lanes 16+k (and 48+k)
      // pack h pairs -> f16, broadcast 8 words
      const float hx = swz_xor1(hlast);
      const int hpi = __builtin_bit_cast(int, __builtin_amdgcn_cvt_pkrtz(hlast, hx));
#pragma unroll
      for (int j = 0; j < 8; ++j)
        hs_pk[j] = __builtin_amdgcn_readlane(hpi, 16 + 2 * j);
      xcur = xnxt;
    }
  }

  // ---- epilogue: out[b] = sigmoid(h . fc_w + fc_b), h fp32 from f-lanes ----
  float s = fcb[0];
#pragma unroll
  for (int k = 0; k < HSZ; ++k) s = fmaf(rl_f(hlast, 16 + k), fcw[k], s);
  if (lane == 0) out[bidx] = rcpf_(1.f + __expf(-s));
}

extern "C" void kernel_launch(void* const* d_in, const int* in_sizes, int n_in,
                              void* d_out, int out_size, void* d_ws, size_t ws_size,
                              hipStream_t stream) {
  const float* x   = (const float*)d_in[0];
  const float* Wih = (const float*)d_in[1];
  const float* Whh = (const float*)d_in[2];
  const float* bih = (const float*)d_in[3];
  const float* bhh = (const float*)d_in[4];
  const float* fcw = (const float*)d_in[5];
  const float* fcb = (const float*)d_in[6];
  float* out = (float*)d_out;

  dim3 grid(BATCH / 4);
  dim3 block(256);
  hipLaunchKernelGGL(lstm_fused, grid, block, 0, stream,
                     x, Wih, Whh, bih, bhh, fcw, fcb, out);
}